// Round 6
// baseline (725.108 us; speedup 1.0000x reference)
//
#include <hip/hip_runtime.h>
#include <hip/hip_bf16.h>
#include <hip/hip_cooperative_groups.h>

namespace cg = cooperative_groups;

#define N_FEAT 3072
#define LATENT 128
#define LOG2PI 1.8378770664093453f

typedef __attribute__((ext_vector_type(8))) short short8;
typedef __attribute__((ext_vector_type(4))) float f32x4;

__device__ __forceinline__ unsigned short f2bf(float x) {
  unsigned int u = __float_as_uint(x);
  u += 0x7FFFu + ((u >> 16) & 1u);
  return (unsigned short)(u >> 16);
}

typedef __attribute__((address_space(1))) const void gas_void;
typedef __attribute__((address_space(3))) void las_void;
__device__ __forceinline__ void gld_lds16(const void* g, void* s) {
  __builtin_amdgcn_global_load_lds((gas_void*)g, (las_void*)s, 16, 0, 0);
}

// ===========================================================================
// prep: blocks 0..47: Mp[b] = Wchunk^T Wchunk partial + Wt[n][k]=bf16(W[k][n])
// (round-5 proven body; works with >=256 threads, t<256 active)
// ===========================================================================
__device__ void prep_body(char* smem, int bid, int t, const float* W,
                          float* Mp, unsigned short* Wt) {
  float* Ws = (float*)smem;  // 64*128 f32 = 32 KB
  int k0 = bid * 64;
  if (t < 256) {
    const float* src = W + (size_t)k0 * 128;
#pragma unroll
    for (int c = 0; c < 8; ++c)
      ((float4*)Ws)[t + 256 * c] = ((const float4*)src)[t + 256 * c];
  }
  __syncthreads();
  if (t < 256) {
    int tr = t >> 4, tc = t & 15;
    float acc[8][8];
#pragma unroll
    for (int r = 0; r < 8; ++r)
#pragma unroll
      for (int c = 0; c < 8; ++c) acc[r][c] = 0.f;
#pragma unroll 2
    for (int k = 0; k < 64; ++k) {
      f32x4 a0 = *(f32x4*)&Ws[k * 128 + 8 * tr];
      f32x4 a1 = *(f32x4*)&Ws[k * 128 + 8 * tr + 4];
      f32x4 b0 = *(f32x4*)&Ws[k * 128 + 8 * tc];
      f32x4 b1 = *(f32x4*)&Ws[k * 128 + 8 * tc + 4];
      float av[8] = {a0.x, a0.y, a0.z, a0.w, a1.x, a1.y, a1.z, a1.w};
      float bv[8] = {b0.x, b0.y, b0.z, b0.w, b1.x, b1.y, b1.z, b1.w};
#pragma unroll
      for (int r = 0; r < 8; ++r)
#pragma unroll
        for (int c = 0; c < 8; ++c) acc[r][c] = fmaf(av[r], bv[c], acc[r][c]);
    }
    float* dst = Mp + (size_t)bid * 16384 + (size_t)(8 * tr) * 128 + 8 * tc;
#pragma unroll
    for (int r = 0; r < 8; ++r) {
      *(f32x4*)(dst + r * 128) =
          (f32x4){acc[r][0], acc[r][1], acc[r][2], acc[r][3]};
      *(f32x4*)(dst + r * 128 + 4) =
          (f32x4){acc[r][4], acc[r][5], acc[r][6], acc[r][7]};
    }
    int n = t >> 1, h = t & 1;
    unsigned pk[16];
#pragma unroll
    for (int c = 0; c < 16; ++c)
      pk[c] = (unsigned)f2bf(Ws[(h * 32 + 2 * c) * 128 + n]) |
              ((unsigned)f2bf(Ws[(h * 32 + 2 * c + 1) * 128 + n]) << 16);
    uint4* wd = (uint4*)(Wt + (size_t)n * N_FEAT + k0 + h * 32);
#pragma unroll
    for (int c = 0; c < 4; ++c)
      wd[c] = make_uint4(pk[4 * c], pk[4 * c + 1], pk[4 * c + 2], pk[4 * c + 3]);
  }
}

// ===========================================================================
// red: blocks 0..63: M = sum of 48 gram partials
// ===========================================================================
__device__ void red_body(int bid, int t, const float* Mp, float* M) {
  if (bid < 64 && t < 256) {
    int i = bid * 256 + t;
    float s = 0.f;
#pragma unroll
    for (int p = 0; p < 48; ++p) s += Mp[(size_t)p * 16384 + i];
    M[i] = s;
  }
}

// ===========================================================================
// inverse: Gauss-Jordan of (M + sigma^2 I) in place, logdet -> scal
// (round-5 proven; t<256 active, barriers unguarded)
// ===========================================================================
__device__ void inverse_body(char* smem, int t, float* M, float* scal,
                             const float* log_var) {
  float* sh = (float*)smem;
  float* PR = sh;        // prow[2][128]
  float* PC = sh + 256;  // pcol[2][128]
  float* DB = sh + 512;  // dbuf[2]
  float* DG = sh + 514;  // diag[128]
  float* RD = sh + 642;  // red[2]
  bool act = t < 256;
  int itr = t >> 4, itc = t & 15;
  float lv = log_var[0];
  float sig2 = expf(lv);
  float a[8][8];
  if (act) {
    const float* srcM = M + (size_t)(8 * itr) * 128 + 8 * itc;
#pragma unroll
    for (int r = 0; r < 8; ++r) {
      f32x4 v0 = *(const f32x4*)(srcM + r * 128);
      f32x4 v1 = *(const f32x4*)(srcM + r * 128 + 4);
      a[r][0] = v0.x; a[r][1] = v0.y; a[r][2] = v0.z; a[r][3] = v0.w;
      a[r][4] = v1.x; a[r][5] = v1.y; a[r][6] = v1.z; a[r][7] = v1.w;
    }
    if (itr == itc) {
#pragma unroll
      for (int r = 0; r < 8; ++r) a[r][r] += sig2;
    }
    if (itr == 0) {
#pragma unroll
      for (int c = 0; c < 8; ++c) PR[8 * itc + c] = a[0][c];
    }
    if (itc == 0) {
#pragma unroll
      for (int r = 0; r < 8; ++r) PC[8 * itr + r] = a[r][0];
    }
    if (t == 0) DB[0] = a[0][0];
  }
  __syncthreads();
  for (int kb = 0; kb < 16; ++kb) {
#pragma unroll
    for (int lk = 0; lk < 8; ++lk) {
      const int k = kb * 8 + lk;
      const int buf = k & 1;
      if (act) {
        float d = DB[buf];
        if (t == 0) DG[k] = d;
        float p = 1.0f / d;
        float pr[8], pc[8];
#pragma unroll
        for (int c = 0; c < 8; ++c) pr[c] = PR[buf * 128 + 8 * itc + c] * p;
#pragma unroll
        for (int r = 0; r < 8; ++r) pc[r] = PC[buf * 128 + 8 * itr + r];
#pragma unroll
        for (int r = 0; r < 8; ++r)
#pragma unroll
          for (int c = 0; c < 8; ++c) a[r][c] = fmaf(-pc[r], pr[c], a[r][c]);
        bool myrow = (itr == (k >> 3));
        bool mycol = (itc == (k >> 3));
        if (myrow) {
#pragma unroll
          for (int c = 0; c < 8; ++c) a[lk][c] = pr[c];
        }
        if (mycol) {
#pragma unroll
          for (int r = 0; r < 8; ++r) a[r][lk] = -p * pc[r];
        }
        if (myrow && mycol) a[lk][lk] = p;
        if (k + 1 < 128) {
          const int nb = buf ^ 1;
          const int nl = (lk + 1) & 7;
          const int nr = (k + 1) >> 3;
          if (itr == nr) {
#pragma unroll
            for (int c = 0; c < 8; ++c) PR[nb * 128 + 8 * itc + c] = a[nl][c];
          }
          if (itc == nr) {
#pragma unroll
            for (int r = 0; r < 8; ++r) PC[nb * 128 + 8 * itr + r] = a[r][nl];
          }
          if (itr == nr && itc == nr) DB[nb] = a[nl][nl];
        }
      }
      __syncthreads();
    }
  }
  if (act) {
    float* dst = M + (size_t)(8 * itr) * 128 + 8 * itc;
#pragma unroll
    for (int r = 0; r < 8; ++r) {
      f32x4 v0 = {a[r][0], a[r][1], a[r][2], a[r][3]};
      f32x4 v1 = {a[r][4], a[r][5], a[r][6], a[r][7]};
      *(f32x4*)(dst + r * 128) = v0;
      *(f32x4*)(dst + r * 128 + 4) = v1;
    }
  }
  float ld = 0.f;
  if (t < 128) ld = logf(DG[t]);
#pragma unroll
  for (int o = 1; o < 64; o <<= 1) ld += __shfl_xor(ld, o);
  if (t == 0) RD[0] = ld;
  if (t == 64) RD[1] = ld;
  __syncthreads();
  if (t == 0) {
    scal[0] = -0.5f * (N_FEAT * LOG2PI + (float)(N_FEAT - LATENT) * lv +
                       (RD[0] + RD[1]));
    scal[1] = expf(-lv);
  }
}

// ===========================================================================
// gemm: one 32-row x K-half tile. 512 thr, BK=128, 12 iters, double-buffered
// LDS, B via global_load_lds (pre-inverse-swizzled source) with counted
// vmcnt(8) across raw barriers; A register-staged with TWO named sets
// (2-iteration prefetch cover). Round-5 proven swizzles.
// ===========================================================================
__device__ void gemm_body(char* smem, int rg, int half, int t,
                          const float* ex, const float* mean,
                          const unsigned short* Wt, float* Tp, float* sqp) {
  char* As = smem;            // [2][32][128] ushort, 8192 B per buf
  char* Bs = smem + 16384;    // [2][128][128] ushort, 32768 B per buf
  int r0 = rg * 32;
  int tg0 = half * 12;
  int lane = t & 63, w = t >> 6;

  int arow = t >> 4, ag = t & 15;
  const float* ep = ex + (size_t)(r0 + arow) * N_FEAT + (size_t)tg0 * 128 + ag * 8;
  const float* mp = mean + (size_t)tg0 * 128 + ag * 8;
  int awoff = arow * 256 + ((ag & 8) + ((ag + arow) & 7)) * 16;

  int sp = lane & 15, rl = lane >> 4;
  const unsigned short* bsrc[4];
#pragma unroll
  for (int j = 0; j < 4; ++j) {
    int n = w * 16 + j * 4 + rl;
    int s = (sp & 8) | ((sp - n) & 7);
    bsrc[j] = Wt + (size_t)n * N_FEAT + (size_t)tg0 * 128 + s * 8;
  }
  char* ldsB0 = Bs + (size_t)w * 4096;
  char* ldsB1 = Bs + 32768 + (size_t)w * 4096;

  int fr = lane & 15, fq = lane >> 4;
  int aoff0[4], aoff1[4], boff[4];
#pragma unroll
  for (int kk = 0; kk < 4; ++kk) {
    int sI = kk * 4 + fq;
    aoff0[kk] = fr * 256 + ((sI & 8) + ((sI + fr) & 7)) * 16;
    int ar1 = 16 + fr;
    aoff1[kk] = ar1 * 256 + ((sI & 8) + ((sI + ar1) & 7)) * 16;
    int n = w * 16 + fr;
    boff[kk] = n * 256 + ((sI & 8) + ((sI + n) & 7)) * 16;
  }

  f32x4 acc0 = {0.f, 0.f, 0.f, 0.f}, acc1 = {0.f, 0.f, 0.f, 0.f};
  float sq = 0.f;
  // two named A register sets (static indexing, rule #20)
  float4 eA, eA2, mA, mA2;   // even tiles
  float4 eB, eB2, mB, mB2;   // odd tiles

  auto loadS0 = [&](int it) {
    const float* p = ep + (size_t)it * 128;
    const float* q = mp + (size_t)it * 128;
    eA = *(const float4*)p;  eA2 = *(const float4*)(p + 4);
    mA = *(const float4*)q;  mA2 = *(const float4*)(q + 4);
  };
  auto loadS1 = [&](int it) {
    const float* p = ep + (size_t)it * 128;
    const float* q = mp + (size_t)it * 128;
    eB = *(const float4*)p;  eB2 = *(const float4*)(p + 4);
    mB = *(const float4*)q;  mB2 = *(const float4*)(q + 4);
  };
  auto packS = [&](const float4& e, const float4& e2, const float4& m,
                   const float4& m2, int bufN) {
    float r0_ = e.x - m.x,   r1_ = e.y - m.y,   r2_ = e.z - m.z,   r3_ = e.w - m.w;
    float r4_ = e2.x - m2.x, r5_ = e2.y - m2.y, r6_ = e2.z - m2.z, r7_ = e2.w - m2.w;
    sq = fmaf(r0_, r0_, sq); sq = fmaf(r1_, r1_, sq);
    sq = fmaf(r2_, r2_, sq); sq = fmaf(r3_, r3_, sq);
    sq = fmaf(r4_, r4_, sq); sq = fmaf(r5_, r5_, sq);
    sq = fmaf(r6_, r6_, sq); sq = fmaf(r7_, r7_, sq);
    uint4 pa;
    pa.x = (unsigned)f2bf(r0_) | ((unsigned)f2bf(r1_) << 16);
    pa.y = (unsigned)f2bf(r2_) | ((unsigned)f2bf(r3_) << 16);
    pa.z = (unsigned)f2bf(r4_) | ((unsigned)f2bf(r5_) << 16);
    pa.w = (unsigned)f2bf(r6_) | ((unsigned)f2bf(r7_) << 16);
    *(uint4*)(As + bufN * 8192 + awoff) = pa;
  };
  auto issueB = [&](int it, int bufN) {
    char* d = bufN ? ldsB1 : ldsB0;
#pragma unroll
    for (int j = 0; j < 4; ++j)
      gld_lds16(bsrc[j] + (size_t)it * 128, d + j * 1024);
  };
  auto mma = [&](int bufN) {
    char* Ab = As + bufN * 8192;
    char* Bb = Bs + bufN * 32768;
#pragma unroll
    for (int kk = 0; kk < 4; ++kk) {
      short8 a0 = *(const short8*)(Ab + aoff0[kk]);
      short8 a1 = *(const short8*)(Ab + aoff1[kk]);
      short8 b  = *(const short8*)(Bb + boff[kk]);
      acc0 = __builtin_amdgcn_mfma_f32_16x16x32_bf16(a0, b, acc0, 0, 0, 0);
      acc1 = __builtin_amdgcn_mfma_f32_16x16x32_bf16(a1, b, acc1, 0, 0, 0);
    }
  };

  // prologue: tiles 0,1 A-loaded; B(0) in flight; tile0 packed; tile2 A-loaded
  loadS0(0);
  loadS1(1);
  __builtin_amdgcn_sched_barrier(0);
  issueB(0, 0);
  packS(eA, eA2, mA, mA2, 0);           // auto-waits A(0)
  loadS0(2);
  asm volatile("s_waitcnt lgkmcnt(0)" ::: "memory");
  __builtin_amdgcn_s_barrier();
  __builtin_amdgcn_sched_barrier(0);

  // iters 0..9 (pairs); per iter: issueB(it+1) -> vmcnt(8) [B(it) done] ->
  // mma(buf) -> pack A(it+1) [2-iter-old loads] -> load A(it+3, clamped)
#pragma unroll
  for (int j = 0; j < 5; ++j) {
    const int it0 = 2 * j;
    // even iteration it0, buf 0
    issueB(it0 + 1, 1);
    asm volatile("s_waitcnt vmcnt(8)" ::: "memory");
    __builtin_amdgcn_sched_barrier(0);
    mma(0);
    packS(eB, eB2, mB, mB2, 1);
    loadS1(it0 + 3 < 12 ? it0 + 3 : 11);
    asm volatile("s_waitcnt lgkmcnt(0)" ::: "memory");
    __builtin_amdgcn_s_barrier();
    __builtin_amdgcn_sched_barrier(0);
    // odd iteration it0+1, buf 1
    issueB(it0 + 2, 0);
    asm volatile("s_waitcnt vmcnt(8)" ::: "memory");
    __builtin_amdgcn_sched_barrier(0);
    mma(1);
    packS(eA, eA2, mA, mA2, 0);
    loadS0(it0 + 4 < 12 ? it0 + 4 : 11);
    asm volatile("s_waitcnt lgkmcnt(0)" ::: "memory");
    __builtin_amdgcn_s_barrier();
    __builtin_amdgcn_sched_barrier(0);
  }
  // iteration 10 (buf 0): last B issue (tile 11)
  issueB(11, 1);
  asm volatile("s_waitcnt vmcnt(8)" ::: "memory");
  __builtin_amdgcn_sched_barrier(0);
  mma(0);
  packS(eB, eB2, mB, mB2, 1);           // tile 11
  asm volatile("s_waitcnt lgkmcnt(0)" ::: "memory");
  __builtin_amdgcn_s_barrier();
  __builtin_amdgcn_sched_barrier(0);
  // iteration 11 (buf 1)
  asm volatile("s_waitcnt vmcnt(0)" ::: "memory");
  __builtin_amdgcn_sched_barrier(0);
  mma(1);

  // sumsq partial
  sq += __shfl_xor(sq, 1); sq += __shfl_xor(sq, 2);
  sq += __shfl_xor(sq, 4); sq += __shfl_xor(sq, 8);
  if (ag == 0) sqp[half * 8192 + r0 + arow] = sq;

  // Tp partial store (D layout col=lane&15, row=fq*4+reg)
  float* tp = Tp + (size_t)half * 1048576 +
              (size_t)(r0 + fq * 4) * 128 + w * 16 + fr;
#pragma unroll
  for (int ii = 0; ii < 4; ++ii) {
    tp[(size_t)ii * 128] = acc0[ii];
    tp[(size_t)ii * 128 + 2048] = acc1[ii];
  }
}

// ===========================================================================
// epi: blocks 0..255 x 32 rows: t = Tp0+Tp1; quad = t^T Minv t;
//      out = scal0 - 0.5*scal1*(sumsq - quad)   (round-5 proven)
// ===========================================================================
__device__ void epi_body(char* smem, int bid, int t, const float* Tp,
                         const float* sqp, const float* Minv,
                         const float* scal, float* out) {
  if (bid >= 256) return;  // uniform per block: safe with internal barriers
  float (*Ts)[132] = (float(*)[132])smem;
  float* rs = (float*)(smem + 32 * 132 * 4);
  int r0 = bid * 32;
  if (t < 256) {
    int sr = t >> 3, sseg = t & 7;
    const float* tp0 = Tp + (size_t)(r0 + sr) * 128 + sseg * 16;
    const float* tp1 = tp0 + 1048576;
#pragma unroll
    for (int c = 0; c < 4; ++c) {
      float4 v0 = *(const float4*)(tp0 + c * 4);
      float4 v1 = *(const float4*)(tp1 + c * 4);
      *(f32x4*)&Ts[sr][sseg * 16 + c * 4] =
          (f32x4){v0.x + v1.x, v0.y + v1.y, v0.z + v1.z, v0.w + v1.w};
    }
    if (t < 32) rs[t] = sqp[r0 + t] + sqp[8192 + r0 + t];
  }
  __syncthreads();
  if (t < 256) {
    int rp = t >> 4, cg2 = t & 15;
    int ra = 2 * rp, rb = ra + 1;
    int c0 = cg2 * 8;
    float ya[8] = {0, 0, 0, 0, 0, 0, 0, 0};
    float yb[8] = {0, 0, 0, 0, 0, 0, 0, 0};
#pragma unroll 4
    for (int j = 0; j < 128; ++j) {
      float tav = Ts[ra][j];
      float tbv = Ts[rb][j];
      float4 v0 = *(const float4*)(Minv + j * LATENT + c0);
      float4 v1 = *(const float4*)(Minv + j * LATENT + c0 + 4);
      ya[0] = fmaf(tav, v0.x, ya[0]); ya[1] = fmaf(tav, v0.y, ya[1]);
      ya[2] = fmaf(tav, v0.z, ya[2]); ya[3] = fmaf(tav, v0.w, ya[3]);
      ya[4] = fmaf(tav, v1.x, ya[4]); ya[5] = fmaf(tav, v1.y, ya[5]);
      ya[6] = fmaf(tav, v1.z, ya[6]); ya[7] = fmaf(tav, v1.w, ya[7]);
      yb[0] = fmaf(tbv, v0.x, yb[0]); yb[1] = fmaf(tbv, v0.y, yb[1]);
      yb[2] = fmaf(tbv, v0.z, yb[2]); yb[3] = fmaf(tbv, v0.w, yb[3]);
      yb[4] = fmaf(tbv, v1.x, yb[4]); yb[5] = fmaf(tbv, v1.y, yb[5]);
      yb[6] = fmaf(tbv, v1.z, yb[6]); yb[7] = fmaf(tbv, v1.w, yb[7]);
    }
    float q0 = 0.f, q1 = 0.f;
#pragma unroll
    for (int c = 0; c < 8; ++c) {
      q0 = fmaf(ya[c], Ts[ra][c0 + c], q0);
      q1 = fmaf(yb[c], Ts[rb][c0 + c], q1);
    }
    q0 += __shfl_xor(q0, 1); q0 += __shfl_xor(q0, 2);
    q0 += __shfl_xor(q0, 4); q0 += __shfl_xor(q0, 8);
    q1 += __shfl_xor(q1, 1); q1 += __shfl_xor(q1, 2);
    q1 += __shfl_xor(q1, 4); q1 += __shfl_xor(q1, 8);
    if (cg2 == 0) {
      float cc = scal[0], is2 = scal[1];
      out[r0 + ra] = cc - 0.5f * is2 * (rs[ra] - q0);
      out[r0 + rb] = cc - 0.5f * is2 * (rs[rb] - q1);
    }
  }
}

// ===========================================================================
// k_all: single cooperative kernel. 512 blocks x 512 thr, 80 KB LDS
// (exactly 2 blocks/CU -> grid co-resident). Phases separated by grid.sync.
// Block 0 in phase G does inverse (~8us) then the (rg=255,half=1) tile.
// ===========================================================================
__global__ __launch_bounds__(512, 4) void k_all(
    const float* __restrict__ ex, const float* __restrict__ W,
    const float* __restrict__ lv, const float* __restrict__ mean,
    float* __restrict__ M, float* __restrict__ scal, float* __restrict__ Tp,
    float* __restrict__ sqp, unsigned short* __restrict__ Wt,
    float* __restrict__ out) {
  __shared__ __align__(16) char smem[81920];
  cg::grid_group grid = cg::this_grid();
  int bid = blockIdx.x, t = threadIdx.x;
  float* Mp = Tp;  // gram partials alias Tp (consumed before Tp written)

  if (bid < 48) prep_body(smem, bid, t, W, Mp, Wt);
  __threadfence();
  grid.sync();

  red_body(bid, t, Mp, M);
  __threadfence();
  grid.sync();

  int rg, half;
  if (bid == 0) {
    inverse_body(smem, t, M, scal, lv);
    __syncthreads();
    rg = 255; half = 1;
  } else {
    int g = bid - 1;             // 0..510: half0 rg0..255, half1 rg0..254
    rg = g & 255; half = g >> 8;
  }
  gemm_body(smem, rg, half, t, ex, mean, Wt, Tp, sqp);
  __threadfence();
  grid.sync();

  epi_body(smem, bid, t, Tp, sqp, M, scal, out);
}

// ===========================================================================
// standalone fallback wrappers (same bodies), used if coop launch fails
// ===========================================================================
__global__ __launch_bounds__(256) void k_prep_s(const float* __restrict__ W,
                                                float* __restrict__ Mp,
                                                unsigned short* __restrict__ Wt) {
  __shared__ __align__(16) char smem[32768];
  prep_body(smem, blockIdx.x, threadIdx.x, W, Mp, Wt);
}
__global__ __launch_bounds__(256) void k_red_s(const float* __restrict__ Mp,
                                               float* __restrict__ M) {
  red_body(blockIdx.x, threadIdx.x, Mp, M);
}
__global__ __launch_bounds__(512, 4) void k_gemm_s(
    const float* __restrict__ ex, const float* __restrict__ mean,
    const unsigned short* __restrict__ Wt, float* __restrict__ M,
    float* __restrict__ scal, const float* __restrict__ lv,
    float* __restrict__ Tp, float* __restrict__ sqp) {
  __shared__ __align__(16) char smem[81920];
  int bid = blockIdx.x, t = threadIdx.x;
  int rg, half;
  if (bid == 0) {
    inverse_body(smem, t, M, scal, lv);
    __syncthreads();
    rg = 255; half = 1;
  } else {
    int g = bid - 1;
    rg = g & 255; half = g >> 8;
  }
  gemm_body(smem, rg, half, t, ex, mean, Wt, Tp, sqp);
}
__global__ __launch_bounds__(256) void k_epi_s(
    const float* __restrict__ Tp, const float* __restrict__ sqp,
    const float* __restrict__ Minv, const float* __restrict__ scal,
    float* __restrict__ out) {
  __shared__ __align__(16) char smem[17024];
  epi_body(smem, blockIdx.x, threadIdx.x, Tp, sqp, Minv, scal, out);
}

// ---------------------------------------------------------------------------
extern "C" void kernel_launch(void* const* d_in, const int* in_sizes, int n_in,
                              void* d_out, int out_size, void* d_ws, size_t ws_size,
                              hipStream_t stream) {
  (void)in_sizes; (void)n_in; (void)out_size; (void)ws_size;
  const float* ex   = (const float*)d_in[0];
  const float* W    = (const float*)d_in[1];
  const float* lv   = (const float*)d_in[2];
  const float* mean = (const float*)d_in[3];
  float* out = (float*)d_out;

  // ws: M(16384f) | scal(64f) | Tp(2x1048576f) | sqp(2x8192f) | Wt(393216 bf16)
  // total 9,306,368 B (round-5 verified to fit: direct path ran and passed)
  float* M = (float*)d_ws;
  float* scal = M + 16384;
  float* Tp = scal + 64;
  float* sqp = Tp + 2097152;
  unsigned short* Wt = (unsigned short*)(sqp + 16384);

  void* kargs[] = {(void*)&ex, (void*)&W, (void*)&lv, (void*)&mean,
                   (void*)&M,  (void*)&scal, (void*)&Tp, (void*)&sqp,
                   (void*)&Wt, (void*)&out};
  hipError_t err = hipLaunchCooperativeKernel((const void*)k_all, dim3(512),
                                              dim3(512), kargs, 0, stream);
  if (err != hipSuccess) {
    (void)hipGetLastError();  // clear sticky error, fall back to 4 launches
    k_prep_s<<<48, 256, 0, stream>>>(W, Tp, Wt);
    k_red_s<<<64, 256, 0, stream>>>(Tp, M);
    k_gemm_s<<<512, 512, 0, stream>>>(ex, mean, Wt, M, scal, lv, Tp, sqp);
    k_epi_s<<<256, 256, 0, stream>>>(Tp, sqp, M, scal, out);
  }
}

// Round 7
// 226.126 us; speedup vs baseline: 3.2067x; 3.2067x over previous
//
#include <hip/hip_runtime.h>
#include <hip/hip_bf16.h>

#define N_FEAT 3072
#define LATENT 128
#define LOG2PI 1.8378770664093453f

typedef __attribute__((ext_vector_type(8))) short short8;
typedef __attribute__((ext_vector_type(4))) float f32x4;

__device__ __forceinline__ unsigned short f2bf(float x) {
  unsigned int u = __float_as_uint(x);
  u += 0x7FFFu + ((u >> 16) & 1u);
  return (unsigned short)(u >> 16);
}

typedef __attribute__((address_space(1))) const void gas_void;
typedef __attribute__((address_space(3))) void las_void;
__device__ __forceinline__ void gld_lds16(const void* g, void* s) {
  __builtin_amdgcn_global_load_lds((gas_void*)g, (las_void*)s, 16, 0, 0);
}

// ===========================================================================
// k_prep: blocks 0..47: Mp[b] = Wchunk^T Wchunk partial (direct store) +
//         Wt[n][k] = bf16(W[k][n])   (round-5 proven)
// ===========================================================================
__global__ __launch_bounds__(256) void k_prep(const float* __restrict__ W,
                                              float* __restrict__ Mp,
                                              unsigned short* __restrict__ Wt) {
  __shared__ __align__(16) float Ws[64 * 128];
  int t = threadIdx.x;
  int k0 = blockIdx.x * 64;
  const float* src = W + (size_t)k0 * 128;
#pragma unroll
  for (int c = 0; c < 8; ++c)
    ((float4*)Ws)[t + 256 * c] = ((const float4*)src)[t + 256 * c];
  __syncthreads();
  int tr = t >> 4, tc = t & 15;
  float acc[8][8];
#pragma unroll
  for (int r = 0; r < 8; ++r)
#pragma unroll
    for (int c = 0; c < 8; ++c) acc[r][c] = 0.f;
#pragma unroll 2
  for (int k = 0; k < 64; ++k) {
    f32x4 a0 = *(f32x4*)&Ws[k * 128 + 8 * tr];
    f32x4 a1 = *(f32x4*)&Ws[k * 128 + 8 * tr + 4];
    f32x4 b0 = *(f32x4*)&Ws[k * 128 + 8 * tc];
    f32x4 b1 = *(f32x4*)&Ws[k * 128 + 8 * tc + 4];
    float av[8] = {a0.x, a0.y, a0.z, a0.w, a1.x, a1.y, a1.z, a1.w};
    float bv[8] = {b0.x, b0.y, b0.z, b0.w, b1.x, b1.y, b1.z, b1.w};
#pragma unroll
    for (int r = 0; r < 8; ++r)
#pragma unroll
      for (int c = 0; c < 8; ++c) acc[r][c] = fmaf(av[r], bv[c], acc[r][c]);
  }
  float* dst = Mp + (size_t)blockIdx.x * 16384 + (size_t)(8 * tr) * 128 + 8 * tc;
#pragma unroll
  for (int r = 0; r < 8; ++r) {
    *(f32x4*)(dst + r * 128) = (f32x4){acc[r][0], acc[r][1], acc[r][2], acc[r][3]};
    *(f32x4*)(dst + r * 128 + 4) = (f32x4){acc[r][4], acc[r][5], acc[r][6], acc[r][7]};
  }
  int n = t >> 1, h = t & 1;
  unsigned pk[16];
#pragma unroll
  for (int c = 0; c < 16; ++c)
    pk[c] = (unsigned)f2bf(Ws[(h * 32 + 2 * c) * 128 + n]) |
            ((unsigned)f2bf(Ws[(h * 32 + 2 * c + 1) * 128 + n]) << 16);
  uint4* wd = (uint4*)(Wt + (size_t)n * N_FEAT + k0 + h * 32);
#pragma unroll
  for (int c = 0; c < 4; ++c)
    wd[c] = make_uint4(pk[4 * c], pk[4 * c + 1], pk[4 * c + 2], pk[4 * c + 3]);
}

// ===========================================================================
// k_red: M = sum of 48 gram partials (round-5 proven)
// ===========================================================================
__global__ __launch_bounds__(256) void k_red(const float* __restrict__ Mp,
                                             float* __restrict__ M) {
  int i = blockIdx.x * 256 + threadIdx.x;
  float s = 0.f;
#pragma unroll
  for (int p = 0; p < 48; ++p) s += Mp[(size_t)p * 16384 + i];
  M[i] = s;
}

// ===========================================================================
// inverse: Gauss-Jordan of (M + sigma^2 I) in place, logdet -> scal
// (round-5/6 proven; t<256 active, barriers unguarded)
// ===========================================================================
__device__ __forceinline__ void inverse_body(char* smem, int t, float* M,
                                             float* scal,
                                             const float* log_var) {
  float* sh = (float*)smem;
  float* PR = sh;        // prow[2][128]
  float* PC = sh + 256;  // pcol[2][128]
  float* DB = sh + 512;  // dbuf[2]
  float* DG = sh + 514;  // diag[128]
  float* RD = sh + 642;  // red[2]
  bool act = t < 256;
  int itr = t >> 4, itc = t & 15;
  float lv = log_var[0];
  float sig2 = expf(lv);
  float a[8][8];
  if (act) {
    const float* srcM = M + (size_t)(8 * itr) * 128 + 8 * itc;
#pragma unroll
    for (int r = 0; r < 8; ++r) {
      f32x4 v0 = *(const f32x4*)(srcM + r * 128);
      f32x4 v1 = *(const f32x4*)(srcM + r * 128 + 4);
      a[r][0] = v0.x; a[r][1] = v0.y; a[r][2] = v0.z; a[r][3] = v0.w;
      a[r][4] = v1.x; a[r][5] = v1.y; a[r][6] = v1.z; a[r][7] = v1.w;
    }
    if (itr == itc) {
#pragma unroll
      for (int r = 0; r < 8; ++r) a[r][r] += sig2;
    }
    if (itr == 0) {
#pragma unroll
      for (int c = 0; c < 8; ++c) PR[8 * itc + c] = a[0][c];
    }
    if (itc == 0) {
#pragma unroll
      for (int r = 0; r < 8; ++r) PC[8 * itr + r] = a[r][0];
    }
    if (t == 0) DB[0] = a[0][0];
  }
  __syncthreads();
  for (int kb = 0; kb < 16; ++kb) {
#pragma unroll
    for (int lk = 0; lk < 8; ++lk) {
      const int k = kb * 8 + lk;
      const int buf = k & 1;
      if (act) {
        float d = DB[buf];
        if (t == 0) DG[k] = d;
        float p = 1.0f / d;
        float pr[8], pc[8];
#pragma unroll
        for (int c = 0; c < 8; ++c) pr[c] = PR[buf * 128 + 8 * itc + c] * p;
#pragma unroll
        for (int r = 0; r < 8; ++r) pc[r] = PC[buf * 128 + 8 * itr + r];
#pragma unroll
        for (int r = 0; r < 8; ++r)
#pragma unroll
          for (int c = 0; c < 8; ++c) a[r][c] = fmaf(-pc[r], pr[c], a[r][c]);
        bool myrow = (itr == (k >> 3));
        bool mycol = (itc == (k >> 3));
        if (myrow) {
#pragma unroll
          for (int c = 0; c < 8; ++c) a[lk][c] = pr[c];
        }
        if (mycol) {
#pragma unroll
          for (int r = 0; r < 8; ++r) a[r][lk] = -p * pc[r];
        }
        if (myrow && mycol) a[lk][lk] = p;
        if (k + 1 < 128) {
          const int nb = buf ^ 1;
          const int nl = (lk + 1) & 7;
          const int nr = (k + 1) >> 3;
          if (itr == nr) {
#pragma unroll
            for (int c = 0; c < 8; ++c) PR[nb * 128 + 8 * itc + c] = a[nl][c];
          }
          if (itc == nr) {
#pragma unroll
            for (int r = 0; r < 8; ++r) PC[nb * 128 + 8 * itr + r] = a[r][nl];
          }
          if (itr == nr && itc == nr) DB[nb] = a[nl][nl];
        }
      }
      __syncthreads();
    }
  }
  if (act) {
    float* dst = M + (size_t)(8 * itr) * 128 + 8 * itc;
#pragma unroll
    for (int r = 0; r < 8; ++r) {
      f32x4 v0 = {a[r][0], a[r][1], a[r][2], a[r][3]};
      f32x4 v1 = {a[r][4], a[r][5], a[r][6], a[r][7]};
      *(f32x4*)(dst + r * 128) = v0;
      *(f32x4*)(dst + r * 128 + 4) = v1;
    }
  }
  float ld = 0.f;
  if (t < 128) ld = logf(DG[t]);
#pragma unroll
  for (int o = 1; o < 64; o <<= 1) ld += __shfl_xor(ld, o);
  if (t == 0) RD[0] = ld;
  if (t == 64) RD[1] = ld;
  __syncthreads();
  if (t == 0) {
    scal[0] = -0.5f * (N_FEAT * LOG2PI + (float)(N_FEAT - LATENT) * lv +
                       (RD[0] + RD[1]));
    scal[1] = expf(-lv);
  }
}

// ===========================================================================
// gemm_body: one 32-row x K-half tile. 512 thr, BK=128, 12 iters, double-
// buffered LDS, B via global_load_lds (pre-inverse-swizzled source) with
// counted vmcnt(8) across raw barriers; A register-staged with TWO named
// sets (2-iteration prefetch cover).  (round-6 correctness-proven)
// ===========================================================================
__device__ __forceinline__ void gemm_body(char* smem, int rg, int half, int t,
                                          const float* ex, const float* mean,
                                          const unsigned short* Wt, float* Tp,
                                          float* sqp) {
  char* As = smem;            // [2][32][128] ushort, 8192 B per buf
  char* Bs = smem + 16384;    // [2][128][128] ushort, 32768 B per buf
  int r0 = rg * 32;
  int tg0 = half * 12;
  int lane = t & 63, w = t >> 6;

  int arow = t >> 4, ag = t & 15;
  const float* ep = ex + (size_t)(r0 + arow) * N_FEAT + (size_t)tg0 * 128 + ag * 8;
  const float* mp = mean + (size_t)tg0 * 128 + ag * 8;
  int awoff = arow * 256 + ((ag & 8) + ((ag + arow) & 7)) * 16;

  int sp = lane & 15, rl = lane >> 4;
  const unsigned short* bsrc[4];
#pragma unroll
  for (int j = 0; j < 4; ++j) {
    int n = w * 16 + j * 4 + rl;
    int s = (sp & 8) | ((sp - n) & 7);
    bsrc[j] = Wt + (size_t)n * N_FEAT + (size_t)tg0 * 128 + s * 8;
  }
  char* ldsB0 = Bs + (size_t)w * 4096;
  char* ldsB1 = Bs + 32768 + (size_t)w * 4096;

  int fr = lane & 15, fq = lane >> 4;
  int aoff0[4], aoff1[4], boff[4];
#pragma unroll
  for (int kk = 0; kk < 4; ++kk) {
    int sI = kk * 4 + fq;
    aoff0[kk] = fr * 256 + ((sI & 8) + ((sI + fr) & 7)) * 16;
    int ar1 = 16 + fr;
    aoff1[kk] = ar1 * 256 + ((sI & 8) + ((sI + ar1) & 7)) * 16;
    int n = w * 16 + fr;
    boff[kk] = n * 256 + ((sI & 8) + ((sI + n) & 7)) * 16;
  }

  f32x4 acc0 = {0.f, 0.f, 0.f, 0.f}, acc1 = {0.f, 0.f, 0.f, 0.f};
  float sq = 0.f;
  float4 eA, eA2, mA, mA2;   // even tiles
  float4 eB, eB2, mB, mB2;   // odd tiles

  auto loadS0 = [&](int it) {
    const float* p = ep + (size_t)it * 128;
    const float* q = mp + (size_t)it * 128;
    eA = *(const float4*)p;  eA2 = *(const float4*)(p + 4);
    mA = *(const float4*)q;  mA2 = *(const float4*)(q + 4);
  };
  auto loadS1 = [&](int it) {
    const float* p = ep + (size_t)it * 128;
    const float* q = mp + (size_t)it * 128;
    eB = *(const float4*)p;  eB2 = *(const float4*)(p + 4);
    mB = *(const float4*)q;  mB2 = *(const float4*)(q + 4);
  };
  auto packS = [&](const float4& e, const float4& e2, const float4& m,
                   const float4& m2, int bufN) {
    float r0_ = e.x - m.x,   r1_ = e.y - m.y,   r2_ = e.z - m.z,   r3_ = e.w - m.w;
    float r4_ = e2.x - m2.x, r5_ = e2.y - m2.y, r6_ = e2.z - m2.z, r7_ = e2.w - m2.w;
    sq = fmaf(r0_, r0_, sq); sq = fmaf(r1_, r1_, sq);
    sq = fmaf(r2_, r2_, sq); sq = fmaf(r3_, r3_, sq);
    sq = fmaf(r4_, r4_, sq); sq = fmaf(r5_, r5_, sq);
    sq = fmaf(r6_, r6_, sq); sq = fmaf(r7_, r7_, sq);
    uint4 pa;
    pa.x = (unsigned)f2bf(r0_) | ((unsigned)f2bf(r1_) << 16);
    pa.y = (unsigned)f2bf(r2_) | ((unsigned)f2bf(r3_) << 16);
    pa.z = (unsigned)f2bf(r4_) | ((unsigned)f2bf(r5_) << 16);
    pa.w = (unsigned)f2bf(r6_) | ((unsigned)f2bf(r7_) << 16);
    *(uint4*)(As + bufN * 8192 + awoff) = pa;
  };
  auto issueB = [&](int it, int bufN) {
    char* d = bufN ? ldsB1 : ldsB0;
#pragma unroll
    for (int j = 0; j < 4; ++j)
      gld_lds16(bsrc[j] + (size_t)it * 128, d + j * 1024);
  };
  auto mma = [&](int bufN) {
    char* Ab = As + bufN * 8192;
    char* Bb = Bs + bufN * 32768;
#pragma unroll
    for (int kk = 0; kk < 4; ++kk) {
      short8 a0 = *(const short8*)(Ab + aoff0[kk]);
      short8 a1 = *(const short8*)(Ab + aoff1[kk]);
      short8 b  = *(const short8*)(Bb + boff[kk]);
      acc0 = __builtin_amdgcn_mfma_f32_16x16x32_bf16(a0, b, acc0, 0, 0, 0);
      acc1 = __builtin_amdgcn_mfma_f32_16x16x32_bf16(a1, b, acc1, 0, 0, 0);
    }
  };

  // prologue: tiles 0,1 A-loaded; B(0) in flight; tile0 packed; tile2 A-loaded
  loadS0(0);
  loadS1(1);
  __builtin_amdgcn_sched_barrier(0);
  issueB(0, 0);
  packS(eA, eA2, mA, mA2, 0);
  loadS0(2);
  asm volatile("s_waitcnt lgkmcnt(0)" ::: "memory");
  __builtin_amdgcn_s_barrier();
  __builtin_amdgcn_sched_barrier(0);

#pragma unroll
  for (int j = 0; j < 5; ++j) {
    const int it0 = 2 * j;
    // even iteration it0, buf 0
    issueB(it0 + 1, 1);
    asm volatile("s_waitcnt vmcnt(8)" ::: "memory");
    __builtin_amdgcn_sched_barrier(0);
    mma(0);
    packS(eB, eB2, mB, mB2, 1);
    loadS1(it0 + 3 < 12 ? it0 + 3 : 11);
    asm volatile("s_waitcnt lgkmcnt(0)" ::: "memory");
    __builtin_amdgcn_s_barrier();
    __builtin_amdgcn_sched_barrier(0);
    // odd iteration it0+1, buf 1
    issueB(it0 + 2, 0);
    asm volatile("s_waitcnt vmcnt(8)" ::: "memory");
    __builtin_amdgcn_sched_barrier(0);
    mma(1);
    packS(eA, eA2, mA, mA2, 0);
    loadS0(it0 + 4 < 12 ? it0 + 4 : 11);
    asm volatile("s_waitcnt lgkmcnt(0)" ::: "memory");
    __builtin_amdgcn_s_barrier();
    __builtin_amdgcn_sched_barrier(0);
  }
  // iteration 10 (buf 0)
  issueB(11, 1);
  asm volatile("s_waitcnt vmcnt(8)" ::: "memory");
  __builtin_amdgcn_sched_barrier(0);
  mma(0);
  packS(eB, eB2, mB, mB2, 1);
  asm volatile("s_waitcnt lgkmcnt(0)" ::: "memory");
  __builtin_amdgcn_s_barrier();
  __builtin_amdgcn_sched_barrier(0);
  // iteration 11 (buf 1)
  asm volatile("s_waitcnt vmcnt(0)" ::: "memory");
  __builtin_amdgcn_sched_barrier(0);
  mma(1);

  // sumsq partial
  sq += __shfl_xor(sq, 1); sq += __shfl_xor(sq, 2);
  sq += __shfl_xor(sq, 4); sq += __shfl_xor(sq, 8);
  if (ag == 0) sqp[half * 8192 + r0 + arow] = sq;

  // Tp partial store (D layout col=lane&15, row=fq*4+reg)
  float* tp = Tp + (size_t)half * 1048576 +
              (size_t)(r0 + fq * 4) * 128 + w * 16 + fr;
#pragma unroll
  for (int ii = 0; ii < 4; ++ii) {
    tp[(size_t)ii * 128] = acc0[ii];
    tp[(size_t)ii * 128 + 2048] = acc1[ii];
  }
}

// ===========================================================================
// k_gemm: 512 blocks. Block 0: inverse (~10us) then tile (rg=255, half=1);
//         blocks 1..511: one tile each. No dual-length block -> flat tail.
// ===========================================================================
__global__ __launch_bounds__(512, 4) void k_gemm(
    const float* __restrict__ ex, const float* __restrict__ mean,
    const unsigned short* __restrict__ Wt, float* __restrict__ M,
    float* __restrict__ scal, const float* __restrict__ lv,
    float* __restrict__ Tp, float* __restrict__ sqp) {
  __shared__ __align__(16) char smem[81920];
  int bid = blockIdx.x, t = threadIdx.x;
  int rg, half;
  if (bid == 0) {
    inverse_body(smem, t, M, scal, lv);
    __syncthreads();
    rg = 255; half = 1;
  } else {
    int g = bid - 1;             // 0..510: half0 rg0..255, half1 rg0..254
    rg = g & 255; half = g >> 8;
  }
  gemm_body(smem, rg, half, t, ex, mean, Wt, Tp, sqp);
}

// ===========================================================================
// k_epi: 256 blocks x 32 rows: t = Tp0+Tp1; quad = t^T Minv t;
//        out = scal0 - 0.5*scal1*(sumsq - quad)   (round-5 proven)
// ===========================================================================
__global__ __launch_bounds__(256) void k_epi(const float* __restrict__ Tp,
                                             const float* __restrict__ sqp,
                                             const float* __restrict__ Minv,
                                             const float* __restrict__ scal,
                                             float* __restrict__ out) {
  __shared__ __align__(16) float Ts[32][132];
  __shared__ float rs[32];
  int t = threadIdx.x;
  int r0 = blockIdx.x * 32;
  int sr = t >> 3, sseg = t & 7;
  const float* tp0 = Tp + (size_t)(r0 + sr) * 128 + sseg * 16;
  const float* tp1 = tp0 + 1048576;
#pragma unroll
  for (int c = 0; c < 4; ++c) {
    float4 v0 = *(const float4*)(tp0 + c * 4);
    float4 v1 = *(const float4*)(tp1 + c * 4);
    *(f32x4*)&Ts[sr][sseg * 16 + c * 4] =
        (f32x4){v0.x + v1.x, v0.y + v1.y, v0.z + v1.z, v0.w + v1.w};
  }
  if (t < 32) rs[t] = sqp[r0 + t] + sqp[8192 + r0 + t];
  __syncthreads();

  int rp = t >> 4, cg2 = t & 15;
  int ra = 2 * rp, rb = ra + 1;
  int c0 = cg2 * 8;
  float ya[8] = {0, 0, 0, 0, 0, 0, 0, 0};
  float yb[8] = {0, 0, 0, 0, 0, 0, 0, 0};
#pragma unroll 4
  for (int j = 0; j < 128; ++j) {
    float tav = Ts[ra][j];
    float tbv = Ts[rb][j];
    float4 v0 = *(const float4*)(Minv + j * LATENT + c0);
    float4 v1 = *(const float4*)(Minv + j * LATENT + c0 + 4);
    ya[0] = fmaf(tav, v0.x, ya[0]); ya[1] = fmaf(tav, v0.y, ya[1]);
    ya[2] = fmaf(tav, v0.z, ya[2]); ya[3] = fmaf(tav, v0.w, ya[3]);
    ya[4] = fmaf(tav, v1.x, ya[4]); ya[5] = fmaf(tav, v1.y, ya[5]);
    ya[6] = fmaf(tav, v1.z, ya[6]); ya[7] = fmaf(tav, v1.w, ya[7]);
    yb[0] = fmaf(tbv, v0.x, yb[0]); yb[1] = fmaf(tbv, v0.y, yb[1]);
    yb[2] = fmaf(tbv, v0.z, yb[2]); yb[3] = fmaf(tbv, v0.w, yb[3]);
    yb[4] = fmaf(tbv, v1.x, yb[4]); yb[5] = fmaf(tbv, v1.y, yb[5]);
    yb[6] = fmaf(tbv, v1.z, yb[6]); yb[7] = fmaf(tbv, v1.w, yb[7]);
  }
  float q0 = 0.f, q1 = 0.f;
#pragma unroll
  for (int c = 0; c < 8; ++c) {
    q0 = fmaf(ya[c], Ts[ra][c0 + c], q0);
    q1 = fmaf(yb[c], Ts[rb][c0 + c], q1);
  }
  q0 += __shfl_xor(q0, 1); q0 += __shfl_xor(q0, 2);
  q0 += __shfl_xor(q0, 4); q0 += __shfl_xor(q0, 8);
  q1 += __shfl_xor(q1, 1); q1 += __shfl_xor(q1, 2);
  q1 += __shfl_xor(q1, 4); q1 += __shfl_xor(q1, 8);
  if (cg2 == 0) {
    float cc = scal[0], is2 = scal[1];
    out[r0 + ra] = cc - 0.5f * is2 * (rs[ra] - q0);
    out[r0 + rb] = cc - 0.5f * is2 * (rs[rb] - q1);
  }
}

// ---------------------------------------------------------------------------
extern "C" void kernel_launch(void* const* d_in, const int* in_sizes, int n_in,
                              void* d_out, int out_size, void* d_ws, size_t ws_size,
                              hipStream_t stream) {
  (void)in_sizes; (void)n_in; (void)out_size; (void)ws_size;
  const float* ex   = (const float*)d_in[0];
  const float* W    = (const float*)d_in[1];
  const float* lv   = (const float*)d_in[2];
  const float* mean = (const float*)d_in[3];
  float* out = (float*)d_out;

  // ws: M(16384f) | scal(64f) | Tp(2x1048576f) | sqp(2x8192f) | Wt(393216 bf16)
  // total 9,306,368 B (round-5/6 verified to fit).
  // Mp (48x16384f) ALIASES Tp: consumed by k_red before k_gemm writes Tp.
  float* M = (float*)d_ws;
  float* scal = M + 16384;
  float* Tp = scal + 64;
  float* sqp = Tp + 2097152;
  unsigned short* Wt = (unsigned short*)(sqp + 16384);
  float* Mp = Tp;

  k_prep<<<48, 256, 0, stream>>>(W, Mp, Wt);
  k_red<<<64, 256, 0, stream>>>(Mp, M);
  k_gemm<<<512, 512, 0, stream>>>(ex, mean, Wt, M, scal, lv, Tp, sqp);
  k_epi<<<256, 256, 0, stream>>>(Tp, sqp, M, scal, out);
}